// Round 4
// baseline (4687.688 us; speedup 1.0000x reference)
//
#include <hip/hip_runtime.h>
#include <hip/hip_bf16.h>

typedef __bf16 bf16x8 __attribute__((ext_vector_type(8)));
typedef float  f32x4  __attribute__((ext_vector_type(4)));

#define B_ 4
#define T_ 2048
#define H_ 16
#define D_ 64
#define C_ 1024
#define M_ 8192                    // B*T
#define NE_ ((size_t)M_ * C_)      // elems per (M,C) tensor

// ---------------------------------------------------------------------------
// Probe: flag=1 if inputs are fp32, flag=0 if bf16. Reading fp32 data as bf16
// exposes uniform-random mantissa halves -> |values| >> 100 (or NaN) with
// probability ~1 over 2048 samples; genuine bf16 N(0,1) data maxes ~6.
// ---------------------------------------------------------------------------
__global__ void probe_dtype(const unsigned short* __restrict__ x,
                            int* __restrict__ flag)
{
  __shared__ float red[256];
  float m = 0.0f;
  for (int i = threadIdx.x; i < 4096; i += 256) {
    unsigned int u = ((unsigned int)x[i]) << 16;
    float v = fabsf(__uint_as_float(u));
    if (!(v <= 1e30f)) v = 1e31f;            // NaN/Inf -> huge
    m = fmaxf(m, v);
  }
  red[threadIdx.x] = m;
  __syncthreads();
  for (int s = 128; s > 0; s >>= 1) {
    if (threadIdx.x < s) red[threadIdx.x] = fmaxf(red[threadIdx.x], red[threadIdx.x + s]);
    __syncthreads();
  }
  if (threadIdx.x == 0) *flag = (red[0] > 100.0f) ? 1 : 0;
}

// load 8 consecutive elements from a raw (flag-typed) buffer as bf16x8
__device__ __forceinline__ bf16x8 load8_adapt(const void* p, size_t idx, int f)
{
  if (f) {
    const float* pf = (const float*)p + idx;
    float4 a = *(const float4*)pf;
    float4 b = *(const float4*)(pf + 4);
    bf16x8 r;
    r[0] = (__bf16)a.x; r[1] = (__bf16)a.y; r[2] = (__bf16)a.z; r[3] = (__bf16)a.w;
    r[4] = (__bf16)b.x; r[5] = (__bf16)b.y; r[6] = (__bf16)b.z; r[7] = (__bf16)b.w;
    return r;
  }
  return *(const bf16x8*)((const __hip_bfloat16*)p + idx);
}

__device__ __forceinline__ float load1_adapt(const void* p, size_t idx, int f)
{
  if (f) return ((const float*)p)[idx];
  return __bfloat162float(((const __hip_bfloat16*)p)[idx]);
}

// ---------------------------------------------------------------------------
// GEMM: C = A * Bm^T (A: MxK, Bm: NxK, raw flag-typed inputs, bf16 output).
// 64x64 tile, BK=32, mfma_f32_16x16x32_bf16, fp32 accum.
// ---------------------------------------------------------------------------
__global__ __launch_bounds__(256) void gemm_in(
    const int* __restrict__ flagp,
    const void* __restrict__ A, const void* __restrict__ Bm,
    __hip_bfloat16* __restrict__ C, int M, int N, int K)
{
  __shared__ alignas(16) __hip_bfloat16 As[64][40];
  __shared__ alignas(16) __hip_bfloat16 Bs[64][40];

  const int f    = *flagp;
  const int tid  = threadIdx.x;
  const int wave = tid >> 6;
  const int lane = tid & 63;
  const int m0 = blockIdx.x * 64;
  const int n0 = blockIdx.y * 64;
  const int lrow = tid >> 2;
  const int lcol = (tid & 3) * 8;

  f32x4 acc[4];
#pragma unroll
  for (int i = 0; i < 4; i++) acc[i] = (f32x4){0.f, 0.f, 0.f, 0.f};

  const int mrow = wave * 16 + (lane & 15);
  const int kq   = (lane >> 4) * 8;

  for (int k0 = 0; k0 < K; k0 += 32) {
    bf16x8 av = load8_adapt(A,  (size_t)(m0 + lrow) * K + k0 + lcol, f);
    bf16x8 bv = load8_adapt(Bm, (size_t)(n0 + lrow) * K + k0 + lcol, f);
    *(bf16x8*)&As[lrow][lcol] = av;
    *(bf16x8*)&Bs[lrow][lcol] = bv;
    __syncthreads();

    bf16x8 a = *(const bf16x8*)&As[mrow][kq];
#pragma unroll
    for (int nt = 0; nt < 4; nt++) {
      bf16x8 b = *(const bf16x8*)&Bs[nt * 16 + (lane & 15)][kq];
      acc[nt] = __builtin_amdgcn_mfma_f32_16x16x32_bf16(a, b, acc[nt], 0, 0, 0);
    }
    __syncthreads();
  }

  const int col = lane & 15;
  const int rb  = (lane >> 4) * 4;
#pragma unroll
  for (int nt = 0; nt < 4; nt++)
#pragma unroll
    for (int r = 0; r < 4; r++)
      C[(size_t)(m0 + wave * 16 + rb + r) * N + n0 + nt * 16 + col] =
          __float2bfloat16(acc[nt][r]);
}

// ---------------------------------------------------------------------------
// Final GEMM: A bf16, Bm raw flag-typed, C stored in the flag dtype.
// ---------------------------------------------------------------------------
__global__ __launch_bounds__(256) void gemm_out(
    const int* __restrict__ flagp,
    const __hip_bfloat16* __restrict__ A, const void* __restrict__ Bm,
    void* __restrict__ C, int M, int N, int K)
{
  __shared__ alignas(16) __hip_bfloat16 As[64][40];
  __shared__ alignas(16) __hip_bfloat16 Bs[64][40];

  const int f    = *flagp;
  const int tid  = threadIdx.x;
  const int wave = tid >> 6;
  const int lane = tid & 63;
  const int m0 = blockIdx.x * 64;
  const int n0 = blockIdx.y * 64;
  const int lrow = tid >> 2;
  const int lcol = (tid & 3) * 8;

  f32x4 acc[4];
#pragma unroll
  for (int i = 0; i < 4; i++) acc[i] = (f32x4){0.f, 0.f, 0.f, 0.f};

  const int mrow = wave * 16 + (lane & 15);
  const int kq   = (lane >> 4) * 8;

  for (int k0 = 0; k0 < K; k0 += 32) {
    bf16x8 av = *(const bf16x8*)(A + (size_t)(m0 + lrow) * K + k0 + lcol);
    bf16x8 bv = load8_adapt(Bm, (size_t)(n0 + lrow) * K + k0 + lcol, f);
    *(bf16x8*)&As[lrow][lcol] = av;
    *(bf16x8*)&Bs[lrow][lcol] = bv;
    __syncthreads();

    bf16x8 a = *(const bf16x8*)&As[mrow][kq];
#pragma unroll
    for (int nt = 0; nt < 4; nt++) {
      bf16x8 b = *(const bf16x8*)&Bs[nt * 16 + (lane & 15)][kq];
      acc[nt] = __builtin_amdgcn_mfma_f32_16x16x32_bf16(a, b, acc[nt], 0, 0, 0);
    }
    __syncthreads();
  }

  const int col = lane & 15;
  const int rb  = (lane >> 4) * 4;
#pragma unroll
  for (int nt = 0; nt < 4; nt++)
#pragma unroll
    for (int r = 0; r < 4; r++) {
      size_t idx = (size_t)(m0 + wave * 16 + rb + r) * N + n0 + nt * 16 + col;
      if (f) ((float*)C)[idx] = acc[nt][r];
      else   ((__hip_bfloat16*)C)[idx] = __float2bfloat16(acc[nt][r]);
    }
}

// ---------------------------------------------------------------------------
// Fused rmsnorm+RoPE on q,k (bf16, in place) + v mix (bf16 in place, v1 raw).
// One wave = one (b,t,h) head row.
// ---------------------------------------------------------------------------
__global__ __launch_bounds__(256) void fuse_rope_vmix(
    const int* __restrict__ flagp,
    __hip_bfloat16* __restrict__ q,
    __hip_bfloat16* __restrict__ k,
    __hip_bfloat16* __restrict__ v,
    const void* __restrict__ v1,
    const void* __restrict__ lambp)
{
  const int f    = *flagp;
  const int task = blockIdx.x * 4 + (threadIdx.x >> 6);
  const int lane = threadIdx.x & 63;
  const int h  = task & 15;
  const int bt = task >> 4;
  const int t  = bt & (T_ - 1);
  const size_t base = (size_t)bt * C_ + h * D_ + lane;

  const int j = lane & 31;
  const float inv = expf(-(float)j * (9.2103403719761836f / 32.0f));
  const float ang = (float)t * inv;
  const float cs = cosf(ang), sn = sinf(ang);
  const float EPS = 0.0078125f;   // bf16 eps (threshold-insensitive either way)

  {
    float xv = __bfloat162float(q[base]);
    float ss = xv * xv;
#pragma unroll
    for (int off = 32; off >= 1; off >>= 1) ss += __shfl_xor(ss, off);
    float r  = rsqrtf(ss * (1.0f / 64.0f) + EPS);
    float xn = xv * r;
    float pr = __shfl_xor(xn, 32);
    float yv = (lane < 32) ? (xn * cs + pr * sn) : (pr * -sn + xn * cs);
    q[base] = __float2bfloat16(yv);
  }
  {
    float xv = __bfloat162float(k[base]);
    float ss = xv * xv;
#pragma unroll
    for (int off = 32; off >= 1; off >>= 1) ss += __shfl_xor(ss, off);
    float r  = rsqrtf(ss * (1.0f / 64.0f) + EPS);
    float xn = xv * r;
    float pr = __shfl_xor(xn, 32);
    float yv = (lane < 32) ? (xn * cs + pr * sn) : (pr * -sn + xn * cs);
    k[base] = __float2bfloat16(yv);
  }
  {
    float lam = load1_adapt(lambp, 0, f);
    float vv  = __bfloat162float(v[base]);
    float v1v = load1_adapt(v1, base, f);
    v[base] = __float2bfloat16((1.0f - lam) * vv + lam * v1v);
  }
}

// ---------------------------------------------------------------------------
// Flash attention fwd (causal), fp32 VALU, bf16 io. QT=32, KT=64. y may alias
// q (block-local slice RAW only; no __restrict__ on q/y).
// ---------------------------------------------------------------------------
#define QT 32
#define KT 64

__global__ __launch_bounds__(256) void attn_fwd(
    const __hip_bfloat16* q,
    const __hip_bfloat16* __restrict__ k,
    const __hip_bfloat16* __restrict__ v,
    __hip_bfloat16* y)
{
  __shared__ alignas(16) float qs[QT][68];
  __shared__ float ks[KT][65];
  __shared__ alignas(16) float vs[KT][68];
  __shared__ float Ps[QT][68];
  __shared__ float m_run[QT], l_run[QT], alpha_s[QT];

  const int tid  = threadIdx.x;
  const int wave = tid >> 6;
  const int lane = tid & 63;
  const int b = blockIdx.y >> 4, h = blockIdx.y & 15;
  const int q0 = blockIdx.x * QT;

  for (int i = tid; i < QT * 64; i += 256) {
    int r = i >> 6, d = i & 63;
    qs[r][d] = __bfloat162float(q[(size_t)(b * T_ + q0 + r) * C_ + h * D_ + d]);
  }
  if (tid < QT) { m_run[tid] = -1e30f; l_run[tid] = 0.0f; }

  float O[8];
#pragma unroll
  for (int i = 0; i < 8; i++) O[i] = 0.0f;
  const int oq = tid >> 3;
  const int od = (tid & 7) * 8;
  const int qb = wave * 8;
  __syncthreads();

  for (int s0 = 0; s0 < q0 + QT; s0 += KT) {
    for (int i = tid; i < KT * 64; i += 256) {
      int r = i >> 6, d = i & 63;
      size_t g = (size_t)(b * T_ + s0 + r) * C_ + h * D_ + d;
      ks[r][d] = __bfloat162float(k[g]);
      vs[r][d] = __bfloat162float(v[g]);
    }
    __syncthreads();

    float sc[8];
#pragma unroll
    for (int i = 0; i < 8; i++) sc[i] = 0.0f;
    for (int d = 0; d < 64; d += 4) {
      float kv0 = ks[lane][d + 0], kv1 = ks[lane][d + 1];
      float kv2 = ks[lane][d + 2], kv3 = ks[lane][d + 3];
#pragma unroll
      for (int i = 0; i < 8; i++) {
        const float4 qv = *(const float4*)&qs[qb + i][d];
        sc[i] += qv.x * kv0 + qv.y * kv1 + qv.z * kv2 + qv.w * kv3;
      }
    }

    const int sg = s0 + lane;
#pragma unroll
    for (int i = 0; i < 8; i++) {
      const int tg = q0 + qb + i;
      float x = (sg <= tg) ? sc[i] * 0.125f : -1e30f;
      float mx = x;
#pragma unroll
      for (int off = 32; off >= 1; off >>= 1) mx = fmaxf(mx, __shfl_xor(mx, off));
      float m_old = m_run[qb + i];
      float m_new = fmaxf(m_old, mx);
      float p = __expf(x - m_new);
      float su = p;
#pragma unroll
      for (int off = 32; off >= 1; off >>= 1) su += __shfl_xor(su, off);
      if (lane == 0) {
        float al = __expf(m_old - m_new);
        m_run[qb + i]   = m_new;
        l_run[qb + i]   = l_run[qb + i] * al + su;
        alpha_s[qb + i] = al;
      }
      Ps[qb + i][lane] = p;
    }
    __syncthreads();

    float al = alpha_s[oq];
#pragma unroll
    for (int jj = 0; jj < 8; jj++) O[jj] *= al;
    int smax = q0 + QT - s0; if (smax > KT) smax = KT;
    for (int s = 0; s < smax; s++) {
      float p = Ps[oq][s];
      const float4 v0 = *(const float4*)&vs[s][od];
      const float4 v1q = *(const float4*)&vs[s][od + 4];
      O[0] += p * v0.x;  O[1] += p * v0.y;  O[2] += p * v0.z;  O[3] += p * v0.w;
      O[4] += p * v1q.x; O[5] += p * v1q.y; O[6] += p * v1q.z; O[7] += p * v1q.w;
    }
    __syncthreads();
  }

  const float linv = 1.0f / l_run[oq];
  const size_t yb = (size_t)(b * T_ + q0 + oq) * C_ + h * D_ + od;
#pragma unroll
  for (int jj = 0; jj < 8; jj++) y[yb + jj] = __float2bfloat16(O[jj] * linv);
}

// ---------------------------------------------------------------------------
// v1 passthrough: raw byte copy, length & dest offset depend on dtype flag.
// ---------------------------------------------------------------------------
__global__ __launch_bounds__(256) void copy_v1(
    const int* __restrict__ flagp, const void* __restrict__ v1, void* __restrict__ out)
{
  const int f = *flagp;
  const size_t nbytes = NE_ * (f ? 4u : 2u);     // one tensor's bytes
  const uint4* s = (const uint4*)v1;
  uint4* d = (uint4*)((char*)out + nbytes);      // out1 = out + NE elems
  const size_t n16 = nbytes / 16;
  for (size_t i = (size_t)blockIdx.x * 256 + threadIdx.x; i < n16;
       i += (size_t)gridDim.x * 256)
    d[i] = s[i];
}

// ---------------------------------------------------------------------------
extern "C" void kernel_launch(void* const* d_in, const int* in_sizes, int n_in,
                              void* d_out, int out_size, void* d_ws, size_t ws_size,
                              hipStream_t stream)
{
  const void* x    = d_in[0];
  const void* v1   = d_in[1];
  const void* Wq   = d_in[2];
  const void* Wk   = d_in[3];
  const void* Wv   = d_in[4];
  const void* Wp   = d_in[5];
  const void* lamb = d_in[6];

  // Scratch: q (and y alias) in ws bf16 [0, NE*2); flag after it.
  // k in out bytes [0, NE*2) (dead before gemm_out overwrites out0);
  // v in out bytes [NE*2, 2*NE*2) (dead before gemm_out/copy_v1 overwrite).
  // Both regions exist under either out dtype (out >= NE*2*2 bytes).
  __hip_bfloat16* qw = (__hip_bfloat16*)d_ws;
  int* flagp = (int*)((char*)d_ws + NE_ * 2);
  __hip_bfloat16* kw = (__hip_bfloat16*)d_out;
  __hip_bfloat16* vw = (__hip_bfloat16*)((char*)d_out + NE_ * 2);

  probe_dtype<<<1, 256, 0, stream>>>((const unsigned short*)x, flagp);

  dim3 gg(M_ / 64, C_ / 64);
  gemm_in<<<gg, 256, 0, stream>>>(flagp, x, Wq, qw, M_, C_, C_);
  gemm_in<<<gg, 256, 0, stream>>>(flagp, x, Wk, kw, M_, C_, C_);
  gemm_in<<<gg, 256, 0, stream>>>(flagp, x, Wv, vw, M_, C_, C_);
  fuse_rope_vmix<<<(M_ * H_) / 4, 256, 0, stream>>>(flagp, qw, kw, vw, v1, lamb);
  attn_fwd<<<dim3(T_ / QT, B_ * H_), 256, 0, stream>>>(qw, kw, vw, qw);
  gemm_out<<<gg, 256, 0, stream>>>(flagp, qw, Wp, d_out, M_, C_, C_);
  copy_v1<<<8192, 256, 0, stream>>>(flagp, v1, d_out);
}

// Round 6
// 599.488 us; speedup vs baseline: 7.8195x; 7.8195x over previous
//
#include <hip/hip_runtime.h>
#include <hip/hip_bf16.h>

typedef __bf16 bf16x8 __attribute__((ext_vector_type(8)));
typedef float  f32x4  __attribute__((ext_vector_type(4)));

#define B_ 4
#define T_ 2048
#define H_ 16
#define D_ 64
#define C_ 1024
#define M_ 8192                    // B*T
#define NE_ ((size_t)M_ * C_)      // elems per (M,C) tensor

// ---------------------------------------------------------------------------
// Probe: flag=1 if inputs are fp32, flag=0 if bf16.
// ---------------------------------------------------------------------------
__global__ void probe_dtype(const unsigned short* __restrict__ x,
                            int* __restrict__ flag)
{
  __shared__ float red[256];
  float m = 0.0f;
  for (int i = threadIdx.x; i < 4096; i += 256) {
    unsigned int u = ((unsigned int)x[i]) << 16;
    float v = fabsf(__uint_as_float(u));
    if (!(v <= 1e30f)) v = 1e31f;
    m = fmaxf(m, v);
  }
  red[threadIdx.x] = m;
  __syncthreads();
  for (int s = 128; s > 0; s >>= 1) {
    if (threadIdx.x < s) red[threadIdx.x] = fmaxf(red[threadIdx.x], red[threadIdx.x + s]);
    __syncthreads();
  }
  if (threadIdx.x == 0) *flag = (red[0] > 100.0f) ? 1 : 0;
}

__device__ __forceinline__ bf16x8 load8_adapt(const void* p, size_t idx, int f)
{
  if (f) {
    const float* pf = (const float*)p + idx;
    float4 a = *(const float4*)pf;
    float4 b = *(const float4*)(pf + 4);
    bf16x8 r;
    r[0] = (__bf16)a.x; r[1] = (__bf16)a.y; r[2] = (__bf16)a.z; r[3] = (__bf16)a.w;
    r[4] = (__bf16)b.x; r[5] = (__bf16)b.y; r[6] = (__bf16)b.z; r[7] = (__bf16)b.w;
    return r;
  }
  return *(const bf16x8*)((const __hip_bfloat16*)p + idx);
}

__device__ __forceinline__ float load1_adapt(const void* p, size_t idx, int f)
{
  if (f) return ((const float*)p)[idx];
  return __bfloat162float(((const __hip_bfloat16*)p)[idx]);
}

// ---------------------------------------------------------------------------
// GEMM: C = A * Bm^T (A: MxK, Bm: NxK, raw flag-typed inputs, bf16 output).
// ---------------------------------------------------------------------------
__global__ __launch_bounds__(256) void gemm_in(
    const int* __restrict__ flagp,
    const void* __restrict__ A, const void* __restrict__ Bm,
    __hip_bfloat16* __restrict__ C, int M, int N, int K)
{
  __shared__ alignas(16) __hip_bfloat16 As[64][40];
  __shared__ alignas(16) __hip_bfloat16 Bs[64][40];

  const int f    = *flagp;
  const int tid  = threadIdx.x;
  const int wave = tid >> 6;
  const int lane = tid & 63;
  const int m0 = blockIdx.x * 64;
  const int n0 = blockIdx.y * 64;
  const int lrow = tid >> 2;
  const int lcol = (tid & 3) * 8;

  f32x4 acc[4];
#pragma unroll
  for (int i = 0; i < 4; i++) acc[i] = (f32x4){0.f, 0.f, 0.f, 0.f};

  const int mrow = wave * 16 + (lane & 15);
  const int kq   = (lane >> 4) * 8;

  for (int k0 = 0; k0 < K; k0 += 32) {
    bf16x8 av = load8_adapt(A,  (size_t)(m0 + lrow) * K + k0 + lcol, f);
    bf16x8 bv = load8_adapt(Bm, (size_t)(n0 + lrow) * K + k0 + lcol, f);
    *(bf16x8*)&As[lrow][lcol] = av;
    *(bf16x8*)&Bs[lrow][lcol] = bv;
    __syncthreads();

    bf16x8 a = *(const bf16x8*)&As[mrow][kq];
#pragma unroll
    for (int nt = 0; nt < 4; nt++) {
      bf16x8 b = *(const bf16x8*)&Bs[nt * 16 + (lane & 15)][kq];
      acc[nt] = __builtin_amdgcn_mfma_f32_16x16x32_bf16(a, b, acc[nt], 0, 0, 0);
    }
    __syncthreads();
  }

  const int col = lane & 15;
  const int rb  = (lane >> 4) * 4;
#pragma unroll
  for (int nt = 0; nt < 4; nt++)
#pragma unroll
    for (int r = 0; r < 4; r++)
      C[(size_t)(m0 + wave * 16 + rb + r) * N + n0 + nt * 16 + col] =
          __float2bfloat16(acc[nt][r]);
}

// ---------------------------------------------------------------------------
// Final GEMM: A bf16, Bm raw flag-typed, C stored in the flag dtype.
// ---------------------------------------------------------------------------
__global__ __launch_bounds__(256) void gemm_out(
    const int* __restrict__ flagp,
    const __hip_bfloat16* __restrict__ A, const void* __restrict__ Bm,
    void* __restrict__ C, int M, int N, int K)
{
  __shared__ alignas(16) __hip_bfloat16 As[64][40];
  __shared__ alignas(16) __hip_bfloat16 Bs[64][40];

  const int f    = *flagp;
  const int tid  = threadIdx.x;
  const int wave = tid >> 6;
  const int lane = tid & 63;
  const int m0 = blockIdx.x * 64;
  const int n0 = blockIdx.y * 64;
  const int lrow = tid >> 2;
  const int lcol = (tid & 3) * 8;

  f32x4 acc[4];
#pragma unroll
  for (int i = 0; i < 4; i++) acc[i] = (f32x4){0.f, 0.f, 0.f, 0.f};

  const int mrow = wave * 16 + (lane & 15);
  const int kq   = (lane >> 4) * 8;

  for (int k0 = 0; k0 < K; k0 += 32) {
    bf16x8 av = *(const bf16x8*)(A + (size_t)(m0 + lrow) * K + k0 + lcol);
    bf16x8 bv = load8_adapt(Bm, (size_t)(n0 + lrow) * K + k0 + lcol, f);
    *(bf16x8*)&As[lrow][lcol] = av;
    *(bf16x8*)&Bs[lrow][lcol] = bv;
    __syncthreads();

    bf16x8 a = *(const bf16x8*)&As[mrow][kq];
#pragma unroll
    for (int nt = 0; nt < 4; nt++) {
      bf16x8 b = *(const bf16x8*)&Bs[nt * 16 + (lane & 15)][kq];
      acc[nt] = __builtin_amdgcn_mfma_f32_16x16x32_bf16(a, b, acc[nt], 0, 0, 0);
    }
    __syncthreads();
  }

  const int col = lane & 15;
  const int rb  = (lane >> 4) * 4;
#pragma unroll
  for (int nt = 0; nt < 4; nt++)
#pragma unroll
    for (int r = 0; r < 4; r++) {
      size_t idx = (size_t)(m0 + wave * 16 + rb + r) * N + n0 + nt * 16 + col;
      if (f) ((float*)C)[idx] = acc[nt][r];
      else   ((__hip_bfloat16*)C)[idx] = __float2bfloat16(acc[nt][r]);
    }
}

// ---------------------------------------------------------------------------
// Fused rmsnorm+RoPE on q,k (bf16, in place) + v mix (bf16 in place, v1 raw).
// ---------------------------------------------------------------------------
__global__ __launch_bounds__(256) void fuse_rope_vmix(
    const int* __restrict__ flagp,
    __hip_bfloat16* __restrict__ q,
    __hip_bfloat16* __restrict__ k,
    __hip_bfloat16* __restrict__ v,
    const void* __restrict__ v1,
    const void* __restrict__ lambp)
{
  const int f    = *flagp;
  const int task = blockIdx.x * 4 + (threadIdx.x >> 6);
  const int lane = threadIdx.x & 63;
  const int h  = task & 15;
  const int bt = task >> 4;
  const int t  = bt & (T_ - 1);
  const size_t base = (size_t)bt * C_ + h * D_ + lane;

  const int j = lane & 31;
  const float inv = expf(-(float)j * (9.2103403719761836f / 32.0f));
  const float ang = (float)t * inv;
  const float cs = cosf(ang), sn = sinf(ang);
  const float EPS = 0.0078125f;

  {
    float xv = __bfloat162float(q[base]);
    float ss = xv * xv;
#pragma unroll
    for (int off = 32; off >= 1; off >>= 1) ss += __shfl_xor(ss, off);
    float r  = rsqrtf(ss * (1.0f / 64.0f) + EPS);
    float xn = xv * r;
    float pr = __shfl_xor(xn, 32);
    float yv = (lane < 32) ? (xn * cs + pr * sn) : (pr * -sn + xn * cs);
    q[base] = __float2bfloat16(yv);
  }
  {
    float xv = __bfloat162float(k[base]);
    float ss = xv * xv;
#pragma unroll
    for (int off = 32; off >= 1; off >>= 1) ss += __shfl_xor(ss, off);
    float r  = rsqrtf(ss * (1.0f / 64.0f) + EPS);
    float xn = xv * r;
    float pr = __shfl_xor(xn, 32);
    float yv = (lane < 32) ? (xn * cs + pr * sn) : (pr * -sn + xn * cs);
    k[base] = __float2bfloat16(yv);
  }
  {
    float lam = load1_adapt(lambp, 0, f);
    float vv  = __bfloat162float(v[base]);
    float v1v = load1_adapt(v1, base, f);
    v[base] = __float2bfloat16((1.0f - lam) * vv + lam * v1v);
  }
}

// ---------------------------------------------------------------------------
// MFMA flash attention fwd (causal). Block: 256 thr = 4 waves; 64 q-rows per
// block (16 per wave), K-tile 64. S=QK^T and O+=PV both via
// mfma_f32_16x16x32_bf16. Online softmax in-register (C-layout rows).
// y aliases q: block reads q rows [q0,q0+64) only at start, writes same rows
// at end; no other block touches them.
// ---------------------------------------------------------------------------
__global__ __launch_bounds__(256) void attn_mfma(
    const __hip_bfloat16* q,
    const __hip_bfloat16* __restrict__ k,
    const __hip_bfloat16* __restrict__ v,
    __hip_bfloat16* y)
{
  __shared__ alignas(16) __hip_bfloat16 Ks[64][72];     // [s][d], pad->2-way
  __shared__ alignas(16) __hip_bfloat16 VTs[64][88];    // [d][s], stride 88
  __shared__ alignas(16) __bf16 Ps[4][16][72];          // per-wave P [q][s]

  const int tid  = threadIdx.x;
  const int wv   = tid >> 6;
  const int lane = tid & 63;
  const int n16  = lane & 15;
  const int quad = lane >> 4;
  const int b = blockIdx.y >> 4, h = blockIdx.y & 15;
  const int q0 = blockIdx.x * 64;
  const size_t hb = (size_t)b * T_ * C_ + h * D_;   // (b,h) base

  // ---- Q fragments, pre-scaled by 1/8 (exact in bf16) ----
  const int qrow = q0 + wv * 16 + n16;
  bf16x8 aq0 = *(const bf16x8*)(q + hb + (size_t)qrow * C_ + quad * 8);
  bf16x8 aq1 = *(const bf16x8*)(q + hb + (size_t)qrow * C_ + 32 + quad * 8);
#pragma unroll
  for (int j = 0; j < 8; j++) {
    aq0[j] = (__bf16)((float)aq0[j] * 0.125f);
    aq1[j] = (__bf16)((float)aq1[j] * 0.125f);
  }

  f32x4 Ot[4];                       // O: row=quad*4+r, col=d=t*16+n16
#pragma unroll
  for (int t = 0; t < 4; t++) Ot[t] = (f32x4){0.f, 0.f, 0.f, 0.f};
  float m_run[4], l_run[4];
#pragma unroll
  for (int r = 0; r < 4; r++) { m_run[r] = -1e30f; l_run[r] = 0.0f; }

  const int niter = q0 / 64 + 1;
  for (int it = 0; it < niter; it++) {
    const int s0 = it * 64;
    // ---- stage K tile [s][d] ----
    {
      const int r = tid >> 2, c16 = (tid & 3) * 16;
      const __hip_bfloat16* src = k + hb + (size_t)(s0 + r) * C_ + c16;
      *(bf16x8*)&Ks[r][c16]     = *(const bf16x8*)(src);
      *(bf16x8*)&Ks[r][c16 + 8] = *(const bf16x8*)(src + 8);
    }
    // ---- stage V transposed [d][s] (scalar global, b128 LDS write) ----
    {
      const int d = tid & 63;
#pragma unroll
      for (int pp = 0; pp < 2; pp++) {
        const int c = (tid >> 6) + pp * 4;          // s-chunk 0..7
        bf16x8 vv;
#pragma unroll
        for (int j = 0; j < 8; j++)
          vv[j] = *(const __bf16*)(v + hb + (size_t)(s0 + c * 8 + j) * C_ + d);
        *(bf16x8*)&VTs[d][c * 8] = vv;
      }
    }
    __syncthreads();

    // ---- S = Q K^T : 4 col-tiles x 2 k-steps ----
    f32x4 S[4];
#pragma unroll
    for (int t = 0; t < 4; t++) {
      S[t] = (f32x4){0.f, 0.f, 0.f, 0.f};
      bf16x8 b0 = *(const bf16x8*)&Ks[t * 16 + n16][quad * 8];
      bf16x8 b1 = *(const bf16x8*)&Ks[t * 16 + n16][32 + quad * 8];
      S[t] = __builtin_amdgcn_mfma_f32_16x16x32_bf16(aq0, b0, S[t], 0, 0, 0);
      S[t] = __builtin_amdgcn_mfma_f32_16x16x32_bf16(aq1, b1, S[t], 0, 0, 0);
    }

    // ---- causal mask (diagonal iteration only; wave-uniform branch) ----
    if (it == niter - 1) {
#pragma unroll
      for (int t = 0; t < 4; t++) {
        const int sg = s0 + t * 16 + n16;
#pragma unroll
        for (int r = 0; r < 4; r++) {
          const int tg = q0 + wv * 16 + quad * 4 + r;
          if (sg > tg) S[t][r] = -1e30f;
        }
      }
    }

    // ---- online softmax per row r; write P to per-wave LDS ----
#pragma unroll
    for (int r = 0; r < 4; r++) {
      float mx = fmaxf(fmaxf(S[0][r], S[1][r]), fmaxf(S[2][r], S[3][r]));
      mx = fmaxf(mx, __shfl_xor(mx, 1));
      mx = fmaxf(mx, __shfl_xor(mx, 2));
      mx = fmaxf(mx, __shfl_xor(mx, 4));
      mx = fmaxf(mx, __shfl_xor(mx, 8));
      const float mnew = fmaxf(m_run[r], mx);
      const float al   = __expf(m_run[r] - mnew);
      m_run[r] = mnew;
      float p0 = __expf(S[0][r] - mnew), p1 = __expf(S[1][r] - mnew);
      float p2 = __expf(S[2][r] - mnew), p3 = __expf(S[3][r] - mnew);
      float su = p0 + p1 + p2 + p3;
      su += __shfl_xor(su, 1);
      su += __shfl_xor(su, 2);
      su += __shfl_xor(su, 4);
      su += __shfl_xor(su, 8);
      l_run[r] = l_run[r] * al + su;
#pragma unroll
      for (int t = 0; t < 4; t++) Ot[t][r] *= al;
      const int prow = quad * 4 + r;
      Ps[wv][prow][n16]      = (__bf16)p0;
      Ps[wv][prow][16 + n16] = (__bf16)p1;
      Ps[wv][prow][32 + n16] = (__bf16)p2;
      Ps[wv][prow][48 + n16] = (__bf16)p3;
    }

    // ---- O += P V (A = per-wave P, in-wave LDS round-trip; B = VT) ----
    bf16x8 ap0 = *(const bf16x8*)&Ps[wv][n16][quad * 8];
    bf16x8 ap1 = *(const bf16x8*)&Ps[wv][n16][32 + quad * 8];
#pragma unroll
    for (int t = 0; t < 4; t++) {
      bf16x8 b0 = *(const bf16x8*)&VTs[t * 16 + n16][quad * 8];
      bf16x8 b1 = *(const bf16x8*)&VTs[t * 16 + n16][32 + quad * 8];
      Ot[t] = __builtin_amdgcn_mfma_f32_16x16x32_bf16(ap0, b0, Ot[t], 0, 0, 0);
      Ot[t] = __builtin_amdgcn_mfma_f32_16x16x32_bf16(ap1, b1, Ot[t], 0, 0, 0);
    }
    __syncthreads();   // before next iter overwrites Ks/VTs
  }

  // ---- epilogue: O / l, store (C-layout scalar stores) ----
  float linv[4];
#pragma unroll
  for (int r = 0; r < 4; r++) linv[r] = 1.0f / l_run[r];
  const int orow = q0 + wv * 16 + quad * 4;
#pragma unroll
  for (int t = 0; t < 4; t++)
#pragma unroll
    for (int r = 0; r < 4; r++)
      y[hb + (size_t)(orow + r) * C_ + t * 16 + n16] =
          __float2bfloat16(Ot[t][r] * linv[r]);
}

// ---------------------------------------------------------------------------
__global__ __launch_bounds__(256) void copy_v1(
    const int* __restrict__ flagp, const void* __restrict__ v1, void* __restrict__ out)
{
  const int f = *flagp;
  const size_t nbytes = NE_ * (f ? 4u : 2u);
  const uint4* s = (const uint4*)v1;
  uint4* d = (uint4*)((char*)out + nbytes);
  const size_t n16 = nbytes / 16;
  for (size_t i = (size_t)blockIdx.x * 256 + threadIdx.x; i < n16;
       i += (size_t)gridDim.x * 256)
    d[i] = s[i];
}

// ---------------------------------------------------------------------------
extern "C" void kernel_launch(void* const* d_in, const int* in_sizes, int n_in,
                              void* d_out, int out_size, void* d_ws, size_t ws_size,
                              hipStream_t stream)
{
  const void* x    = d_in[0];
  const void* v1   = d_in[1];
  const void* Wq   = d_in[2];
  const void* Wk   = d_in[3];
  const void* Wv   = d_in[4];
  const void* Wp   = d_in[5];
  const void* lamb = d_in[6];

  __hip_bfloat16* qw = (__hip_bfloat16*)d_ws;
  int* flagp = (int*)((char*)d_ws + NE_ * 2);
  __hip_bfloat16* kw = (__hip_bfloat16*)d_out;
  __hip_bfloat16* vw = (__hip_bfloat16*)((char*)d_out + NE_ * 2);

  probe_dtype<<<1, 256, 0, stream>>>((const unsigned short*)x, flagp);

  dim3 gg(M_ / 64, C_ / 64);
  gemm_in<<<gg, 256, 0, stream>>>(flagp, x, Wq, qw, M_, C_, C_);
  gemm_in<<<gg, 256, 0, stream>>>(flagp, x, Wk, kw, M_, C_, C_);
  gemm_in<<<gg, 256, 0, stream>>>(flagp, x, Wv, vw, M_, C_, C_);
  fuse_rope_vmix<<<(M_ * H_) / 4, 256, 0, stream>>>(flagp, qw, kw, vw, v1, lamb);
  attn_mfma<<<dim3(T_ / 64, B_ * H_), 256, 0, stream>>>(qw, kw, vw, qw);
  gemm_out<<<gg, 256, 0, stream>>>(flagp, qw, Wp, d_out, M_, C_, C_);
  copy_v1<<<8192, 256, 0, stream>>>(flagp, v1, d_out);
}

// Round 7
// 534.402 us; speedup vs baseline: 8.7718x; 1.1218x over previous
//
#include <hip/hip_runtime.h>
#include <hip/hip_bf16.h>

typedef __bf16 bf16x8 __attribute__((ext_vector_type(8)));
typedef __bf16 bf16x4 __attribute__((ext_vector_type(4)));
typedef float  f32x4  __attribute__((ext_vector_type(4)));

#define B_ 4
#define T_ 2048
#define H_ 16
#define D_ 64
#define C_ 1024
#define M_ 8192                    // B*T
#define NE_ ((size_t)M_ * C_)      // elems per (M,C) tensor

// ---------------------------------------------------------------------------
// Probe: flag=1 if inputs are fp32, flag=0 if bf16.
// ---------------------------------------------------------------------------
__global__ void probe_dtype(const unsigned short* __restrict__ x,
                            int* __restrict__ flag)
{
  __shared__ float red[256];
  float m = 0.0f;
  for (int i = threadIdx.x; i < 4096; i += 256) {
    unsigned int u = ((unsigned int)x[i]) << 16;
    float v = fabsf(__uint_as_float(u));
    if (!(v <= 1e30f)) v = 1e31f;
    m = fmaxf(m, v);
  }
  red[threadIdx.x] = m;
  __syncthreads();
  for (int s = 128; s > 0; s >>= 1) {
    if (threadIdx.x < s) red[threadIdx.x] = fmaxf(red[threadIdx.x], red[threadIdx.x + s]);
    __syncthreads();
  }
  if (threadIdx.x == 0) *flag = (red[0] > 100.0f) ? 1 : 0;
}

__device__ __forceinline__ float load1_adapt(const void* p, size_t idx, int f)
{
  if (f) return ((const float*)p)[idx];
  return __bfloat162float(((const __hip_bfloat16*)p)[idx]);
}

// ---------------------------------------------------------------------------
// Convert a tensor to bf16 (fp32 src if flag, else plain bf16 copy).
// n must be a multiple of 8 * gridstride handling included.
// ---------------------------------------------------------------------------
__global__ __launch_bounds__(256) void cvt_bf16(
    const int* __restrict__ flagp, const void* __restrict__ src,
    __bf16* __restrict__ dst, int n)
{
  const int f = *flagp;
  for (size_t i = ((size_t)blockIdx.x * 256 + threadIdx.x) * 8; i < (size_t)n;
       i += (size_t)gridDim.x * 2048) {
    bf16x8 r;
    if (f) {
      const float* pf = (const float*)src + i;
      float4 a = *(const float4*)pf;
      float4 b = *(const float4*)(pf + 4);
      r[0] = (__bf16)a.x; r[1] = (__bf16)a.y; r[2] = (__bf16)a.z; r[3] = (__bf16)a.w;
      r[4] = (__bf16)b.x; r[5] = (__bf16)b.y; r[6] = (__bf16)b.z; r[7] = (__bf16)b.w;
    } else {
      r = *(const bf16x8*)((const __bf16*)src + i);
    }
    *(bf16x8*)(dst + i) = r;
  }
}

// ---------------------------------------------------------------------------
// async 16B global -> LDS copy (gfx950 global_load_lds dwordx4)
// ---------------------------------------------------------------------------
__device__ __forceinline__ void g2lds16(const __bf16* g, __bf16* l)
{
  __builtin_amdgcn_global_load_lds(
      (const __attribute__((address_space(1))) void*)g,
      (__attribute__((address_space(3))) void*)l, 16, 0, 0);
}

// ---------------------------------------------------------------------------
// m97-style GEMM: C = A * Bm^T. A: MxK bf16, Bm: NxK bf16. 128x128 tile,
// BK=64, 4 waves (2x2), global_load_lds width-16 staging (unpadded LDS —
// required by the wave-uniform-base + lane*16 constraint).
// Output: bf16, or fp32 when (adaptive && *flagp).
// ---------------------------------------------------------------------------
__global__ __launch_bounds__(256) void gemm128(
    const __bf16* __restrict__ A, const __bf16* __restrict__ Bm,
    void* __restrict__ C, int M, int N, int K,
    const int* __restrict__ flagp, int adaptive)
{
  __shared__ __bf16 As[128][64];
  __shared__ __bf16 Bs[128][64];

  const int tid  = threadIdx.x;
  const int wv   = tid >> 6;
  const int lane = tid & 63;
  const int n16  = lane & 15;
  const int quad = lane >> 4;
  const int wm = (wv & 1) * 64, wn = (wv >> 1) * 64;
  const int m0 = blockIdx.x * 128, n0 = blockIdx.y * 128;

  f32x4 acc[4][4];
#pragma unroll
  for (int i = 0; i < 4; i++)
#pragma unroll
    for (int j = 0; j < 4; j++) acc[i][j] = (f32x4){0.f, 0.f, 0.f, 0.f};

  const int trow = tid >> 3;          // 0..31
  const int tcol = (tid & 7) * 8;     // 0..56

  for (int k0 = 0; k0 < K; k0 += 64) {
#pragma unroll
    for (int p = 0; p < 4; p++) {
      g2lds16(A  + (size_t)(m0 + trow + p * 32) * K + k0 + tcol,
              &As[trow + p * 32][tcol]);
      g2lds16(Bm + (size_t)(n0 + trow + p * 32) * K + k0 + tcol,
              &Bs[trow + p * 32][tcol]);
    }
    __syncthreads();   // drains vmcnt(0): LDS is valid

#pragma unroll
    for (int kk = 0; kk < 2; kk++) {
      bf16x8 af[4], bf[4];
#pragma unroll
      for (int i = 0; i < 4; i++) {
        af[i] = *(const bf16x8*)&As[wm + i * 16 + n16][kk * 32 + quad * 8];
        bf[i] = *(const bf16x8*)&Bs[wn + i * 16 + n16][kk * 32 + quad * 8];
      }
#pragma unroll
      for (int i = 0; i < 4; i++)
#pragma unroll
        for (int j = 0; j < 4; j++)
          acc[i][j] = __builtin_amdgcn_mfma_f32_16x16x32_bf16(af[i], bf[j],
                                                              acc[i][j], 0, 0, 0);
    }
    __syncthreads();
  }

  const int f = adaptive ? *flagp : 0;
  const int rb = quad * 4;
#pragma unroll
  for (int i = 0; i < 4; i++)
#pragma unroll
    for (int j = 0; j < 4; j++)
#pragma unroll
      for (int r = 0; r < 4; r++) {
        const size_t idx = (size_t)(m0 + wm + i * 16 + rb + r) * N
                           + n0 + wn + j * 16 + n16;
        if (f) ((float*)C)[idx] = acc[i][j][r];
        else   ((__bf16*)C)[idx] = (__bf16)acc[i][j][r];
      }
}

// ---------------------------------------------------------------------------
// Fused rmsnorm+RoPE on q,k (bf16, in place) + v mix (bf16 in place, v1 raw).
// ---------------------------------------------------------------------------
__global__ __launch_bounds__(256) void fuse_rope_vmix(
    const int* __restrict__ flagp,
    __hip_bfloat16* __restrict__ q,
    __hip_bfloat16* __restrict__ k,
    __hip_bfloat16* __restrict__ v,
    const void* __restrict__ v1,
    const void* __restrict__ lambp)
{
  const int f    = *flagp;
  const int task = blockIdx.x * 4 + (threadIdx.x >> 6);
  const int lane = threadIdx.x & 63;
  const int h  = task & 15;
  const int bt = task >> 4;
  const int t  = bt & (T_ - 1);
  const size_t base = (size_t)bt * C_ + h * D_ + lane;

  const int j = lane & 31;
  const float inv = expf(-(float)j * (9.2103403719761836f / 32.0f));
  const float ang = (float)t * inv;
  const float cs = cosf(ang), sn = sinf(ang);
  const float EPS = 0.0078125f;

  {
    float xv = __bfloat162float(q[base]);
    float ss = xv * xv;
#pragma unroll
    for (int off = 32; off >= 1; off >>= 1) ss += __shfl_xor(ss, off);
    float r  = rsqrtf(ss * (1.0f / 64.0f) + EPS);
    float xn = xv * r;
    float pr = __shfl_xor(xn, 32);
    float yv = (lane < 32) ? (xn * cs + pr * sn) : (pr * -sn + xn * cs);
    q[base] = __float2bfloat16(yv);
  }
  {
    float xv = __bfloat162float(k[base]);
    float ss = xv * xv;
#pragma unroll
    for (int off = 32; off >= 1; off >>= 1) ss += __shfl_xor(ss, off);
    float r  = rsqrtf(ss * (1.0f / 64.0f) + EPS);
    float xn = xv * r;
    float pr = __shfl_xor(xn, 32);
    float yv = (lane < 32) ? (xn * cs + pr * sn) : (pr * -sn + xn * cs);
    k[base] = __float2bfloat16(yv);
  }
  {
    float lam = load1_adapt(lambp, 0, f);
    float vv  = __bfloat162float(v[base]);
    float v1v = load1_adapt(v1, base, f);
    v[base] = __float2bfloat16((1.0f - lam) * vv + lam * v1v);
  }
}

// ---------------------------------------------------------------------------
// MFMA flash attention fwd (causal). 4 waves, 64 q-rows/block, K-tile 64.
// Ps stride 76 (writes 2-way/free; reads 2x ds_read_b64 at min cycles).
// V staged via vector global loads + scalar conflict-free LDS writes.
// Heavy blocks launch first (reversed q0). y aliases q (block-local slice).
// ---------------------------------------------------------------------------
__global__ __launch_bounds__(256) void attn_mfma(
    const __bf16* q,
    const __bf16* __restrict__ k,
    const __bf16* __restrict__ v,
    __bf16* y)
{
  __shared__ alignas(16) __bf16 Ks[64][72];     // [s][d]
  __shared__ alignas(16) __bf16 VTs[64][88];    // [d][s]
  __shared__ alignas(16) __bf16 Ps[4][16][76];  // per-wave P [q][s], stride 76

  const int tid  = threadIdx.x;
  const int wv   = tid >> 6;
  const int lane = tid & 63;
  const int n16  = lane & 15;
  const int quad = lane >> 4;
  const int b = blockIdx.y >> 4, h = blockIdx.y & 15;
  const int q0 = (gridDim.x - 1 - blockIdx.x) * 64;   // heavy blocks first
  const size_t hb = (size_t)b * T_ * C_ + h * D_;

  // ---- Q fragments, pre-scaled by 1/8 (exact in bf16) ----
  const int qrow = q0 + wv * 16 + n16;
  bf16x8 aq0 = *(const bf16x8*)(q + hb + (size_t)qrow * C_ + quad * 8);
  bf16x8 aq1 = *(const bf16x8*)(q + hb + (size_t)qrow * C_ + 32 + quad * 8);
#pragma unroll
  for (int j = 0; j < 8; j++) {
    aq0[j] = (__bf16)((float)aq0[j] * 0.125f);
    aq1[j] = (__bf16)((float)aq1[j] * 0.125f);
  }

  f32x4 Ot[4];
#pragma unroll
  for (int t = 0; t < 4; t++) Ot[t] = (f32x4){0.f, 0.f, 0.f, 0.f};
  float m_run[4], l_run[4];
#pragma unroll
  for (int r = 0; r < 4; r++) { m_run[r] = -1e30f; l_run[r] = 0.0f; }

  const int niter = q0 / 64 + 1;
  for (int it = 0; it < niter; it++) {
    const int s0 = it * 64;
    // ---- stage K tile [s][d] (vector loads + b128 LDS writes) ----
    {
      const int r = tid >> 2, c16 = (tid & 3) * 16;
      const __bf16* src = k + hb + (size_t)(s0 + r) * C_ + c16;
      *(bf16x8*)&Ks[r][c16]     = *(const bf16x8*)(src);
      *(bf16x8*)&Ks[r][c16 + 8] = *(const bf16x8*)(src + 8);
    }
    // ---- stage V transposed [d][s]: vector global load + scalar LDS scatter
    {
      const int sv = lane;                         // V row within tile
#pragma unroll
      for (int pp = 0; pp < 2; pp++) {
        const int dblk = wv + pp * 4;              // 0..7
        bf16x8 vv = *(const bf16x8*)(v + hb + (size_t)(s0 + sv) * C_ + dblk * 8);
#pragma unroll
        for (int j = 0; j < 8; j++) VTs[dblk * 8 + j][sv] = vv[j];
      }
    }
    __syncthreads();

    // ---- S = Q K^T ----
    f32x4 S[4];
#pragma unroll
    for (int t = 0; t < 4; t++) {
      S[t] = (f32x4){0.f, 0.f, 0.f, 0.f};
      bf16x8 b0 = *(const bf16x8*)&Ks[t * 16 + n16][quad * 8];
      bf16x8 b1 = *(const bf16x8*)&Ks[t * 16 + n16][32 + quad * 8];
      S[t] = __builtin_amdgcn_mfma_f32_16x16x32_bf16(aq0, b0, S[t], 0, 0, 0);
      S[t] = __builtin_amdgcn_mfma_f32_16x16x32_bf16(aq1, b1, S[t], 0, 0, 0);
    }

    // ---- causal mask on diagonal iteration ----
    if (it == niter - 1) {
#pragma unroll
      for (int t = 0; t < 4; t++) {
        const int sg = s0 + t * 16 + n16;
#pragma unroll
        for (int r = 0; r < 4; r++) {
          const int tg = q0 + wv * 16 + quad * 4 + r;
          if (sg > tg) S[t][r] = -1e30f;
        }
      }
    }

    // ---- online softmax; P -> per-wave LDS (stride 76: conflict-free) ----
#pragma unroll
    for (int r = 0; r < 4; r++) {
      float mx = fmaxf(fmaxf(S[0][r], S[1][r]), fmaxf(S[2][r], S[3][r]));
      mx = fmaxf(mx, __shfl_xor(mx, 1));
      mx = fmaxf(mx, __shfl_xor(mx, 2));
      mx = fmaxf(mx, __shfl_xor(mx, 4));
      mx = fmaxf(mx, __shfl_xor(mx, 8));
      const float mnew = fmaxf(m_run[r], mx);
      const float al   = __expf(m_run[r] - mnew);
      m_run[r] = mnew;
      float p0 = __expf(S[0][r] - mnew), p1 = __expf(S[1][r] - mnew);
      float p2 = __expf(S[2][r] - mnew), p3 = __expf(S[3][r] - mnew);
      float su = p0 + p1 + p2 + p3;
      su += __shfl_xor(su, 1);
      su += __shfl_xor(su, 2);
      su += __shfl_xor(su, 4);
      su += __shfl_xor(su, 8);
      l_run[r] = l_run[r] * al + su;
#pragma unroll
      for (int t = 0; t < 4; t++) Ot[t][r] *= al;
      const int prow = quad * 4 + r;
      Ps[wv][prow][n16]      = (__bf16)p0;
      Ps[wv][prow][16 + n16] = (__bf16)p1;
      Ps[wv][prow][32 + n16] = (__bf16)p2;
      Ps[wv][prow][48 + n16] = (__bf16)p3;
    }

    // ---- O += P V (A-frag from Ps via 2x b64; B = VT) ----
    bf16x4 l0 = *(const bf16x4*)&Ps[wv][n16][quad * 8];
    bf16x4 l1 = *(const bf16x4*)&Ps[wv][n16][quad * 8 + 4];
    bf16x4 l2 = *(const bf16x4*)&Ps[wv][n16][32 + quad * 8];
    bf16x4 l3 = *(const bf16x4*)&Ps[wv][n16][32 + quad * 8 + 4];
    bf16x8 ap0 = __builtin_shufflevector(l0, l1, 0, 1, 2, 3, 4, 5, 6, 7);
    bf16x8 ap1 = __builtin_shufflevector(l2, l3, 0, 1, 2, 3, 4, 5, 6, 7);
#pragma unroll
    for (int t = 0; t < 4; t++) {
      bf16x8 b0 = *(const bf16x8*)&VTs[t * 16 + n16][quad * 8];
      bf16x8 b1 = *(const bf16x8*)&VTs[t * 16 + n16][32 + quad * 8];
      Ot[t] = __builtin_amdgcn_mfma_f32_16x16x32_bf16(ap0, b0, Ot[t], 0, 0, 0);
      Ot[t] = __builtin_amdgcn_mfma_f32_16x16x32_bf16(ap1, b1, Ot[t], 0, 0, 0);
    }
    __syncthreads();
  }

  // ---- epilogue ----
  float linv[4];
#pragma unroll
  for (int r = 0; r < 4; r++) linv[r] = 1.0f / l_run[r];
  const int orow = q0 + wv * 16 + quad * 4;
#pragma unroll
  for (int t = 0; t < 4; t++)
#pragma unroll
    for (int r = 0; r < 4; r++)
      y[hb + (size_t)(orow + r) * C_ + t * 16 + n16] =
          (__bf16)(Ot[t][r] * linv[r]);
}

// ---------------------------------------------------------------------------
__global__ __launch_bounds__(256) void copy_v1(
    const int* __restrict__ flagp, const void* __restrict__ v1, void* __restrict__ out)
{
  const int f = *flagp;
  const size_t nbytes = NE_ * (f ? 4u : 2u);
  const uint4* s = (const uint4*)v1;
  uint4* d = (uint4*)((char*)out + nbytes);
  const size_t n16 = nbytes / 16;
  for (size_t i = (size_t)blockIdx.x * 256 + threadIdx.x; i < n16;
       i += (size_t)gridDim.x * 256)
    d[i] = s[i];
}

// ---------------------------------------------------------------------------
extern "C" void kernel_launch(void* const* d_in, const int* in_sizes, int n_in,
                              void* d_out, int out_size, void* d_ws, size_t ws_size,
                              hipStream_t stream)
{
  const void* x    = d_in[0];
  const void* v1   = d_in[1];
  const void* Wq   = d_in[2];
  const void* Wk   = d_in[3];
  const void* Wv   = d_in[4];
  const void* Wp   = d_in[5];
  const void* lamb = d_in[6];

  // ws layout (bf16): xb | qw | Wq | Wk | Wv | Wp | flag  (~42 MB)
  __bf16* xb  = (__bf16*)d_ws;
  __bf16* qw  = xb + NE_;
  __bf16* wqb = qw + NE_;
  __bf16* wkb = wqb + (size_t)C_ * C_;
  __bf16* wvb = wkb + (size_t)C_ * C_;
  __bf16* wpb = wvb + (size_t)C_ * C_;
  int* flagp  = (int*)(wpb + (size_t)C_ * C_);
  // k, v staging in d_out (safe under both dtypes; dead before final writes)
  __bf16* kw = (__bf16*)d_out;
  __bf16* vw = (__bf16*)((char*)d_out + NE_ * 2);

  probe_dtype<<<1, 256, 0, stream>>>((const unsigned short*)x, flagp);

  cvt_bf16<<<4096, 256, 0, stream>>>(flagp, x,  xb,  (int)NE_);
  cvt_bf16<<<512,  256, 0, stream>>>(flagp, Wq, wqb, C_ * C_);
  cvt_bf16<<<512,  256, 0, stream>>>(flagp, Wk, wkb, C_ * C_);
  cvt_bf16<<<512,  256, 0, stream>>>(flagp, Wv, wvb, C_ * C_);
  cvt_bf16<<<512,  256, 0, stream>>>(flagp, Wp, wpb, C_ * C_);

  dim3 gg(M_ / 128, C_ / 128);
  gemm128<<<gg, 256, 0, stream>>>(xb, wqb, qw, M_, C_, C_, flagp, 0);
  gemm128<<<gg, 256, 0, stream>>>(xb, wkb, kw, M_, C_, C_, flagp, 0);
  gemm128<<<gg, 256, 0, stream>>>(xb, wvb, vw, M_, C_, C_, flagp, 0);

  fuse_rope_vmix<<<(M_ * H_) / 4, 256, 0, stream>>>(
      flagp, (__hip_bfloat16*)qw, (__hip_bfloat16*)kw, (__hip_bfloat16*)vw,
      v1, lamb);

  attn_mfma<<<dim3(T_ / 64, B_ * H_), 256, 0, stream>>>(qw, kw, vw, qw);

  gemm128<<<gg, 256, 0, stream>>>(qw, wpb, d_out, M_, C_, C_, flagp, 1);
  copy_v1<<<8192, 256, 0, stream>>>(flagp, v1, d_out);
}